// Round 8
// baseline (220.595 us; speedup 1.0000x reference)
//
#include <hip/hip_runtime.h>
#include <hip/hip_bf16.h>

#define BB 4
#define NN 2048
#define NH 4
#define HDD 16
#define FD 64
#define QB 32                 // queries per block (attn)
#define SPLIT 4
#define KPB (NN / SPLIT)      // 512 keys per split
#define KT (KPB / 64)         // 8 tiles of 64 keys
#define L2E 1.44269504088896f

typedef __attribute__((ext_vector_type(8))) short bf16x8;
typedef __attribute__((ext_vector_type(4))) float f32x4;
typedef __attribute__((ext_vector_type(8))) _Float16 f16x8;

union BW { __hip_bfloat16 b; unsigned short u; };

static __device__ inline unsigned pk2(float a, float b) {
    BW x, y;
    x.b = __float2bfloat16(a);
    y.b = __float2bfloat16(b);
    return (unsigned)x.u | ((unsigned)y.u << 16);
}

static __device__ inline float wsum(float v) {
    v += __shfl_xor(v, 1);  v += __shfl_xor(v, 2);  v += __shfl_xor(v, 4);
    v += __shfl_xor(v, 8);  v += __shfl_xor(v, 16); v += __shfl_xor(v, 32);
    return v;
}

// ---------------- Pass 0: blended graph -> fp16, pre-scaled by 1/ln2.
// E[b][q][k] = (fr*learned + (1-fr)*fixed) * L2E. Pure streaming kernel.
__global__ __launch_bounds__(256) void blend_kernel(
    const float* __restrict__ learng, const float* __restrict__ fixedg,
    const float* __restrict__ gfus, _Float16* __restrict__ E)
{
    const float sg = 1.f / (1.f + __expf(-gfus[0]));
    const float fre = sg * L2E, ofre = (1.f - sg) * L2E;
    const size_t base = ((size_t)blockIdx.x * 256 + threadIdx.x) * 32;
    #pragma unroll
    for (int i = 0; i < 32; i += 8) {
        const size_t o = base + i;
        const f32x4 l0 = *(const f32x4*)(learng + o);
        const f32x4 l1 = *(const f32x4*)(learng + o + 4);
        const size_t fo = o & ((size_t)NN * NN - 1);   // fixed graph repeats per batch
        const f32x4 f0 = *(const f32x4*)(fixedg + fo);
        const f32x4 f1 = *(const f32x4*)(fixedg + fo + 4);
        f16x8 e;
        #pragma unroll
        for (int j = 0; j < 4; ++j) {
            e[j]     = (_Float16)(fre * l0[j] + ofre * f0[j]);
            e[4 + j] = (_Float16)(fre * l1[j] + ofre * f1[j]);
        }
        *(f16x8*)(E + o) = e;
    }
}

// ---------------- Pass A: qkv = (feat @ Wqc + bqc) @ Wqe + bqe -> Q_ext/K_ext/Vt (bf16)
// One wave per node, 4 nodes per block; two-stage projection via LDS (no fused W).
// Q_ext row (32): [ q*0.25/ln2 (16) | bf1[h,n,:]/ln2 (8) | 0 (8) ]
// K_ext row (32): [ k           (16) | bf2[h,:,n]     (8) | 0 (8) ]
// Vt[b][h][d][n] = v
__global__ __launch_bounds__(256) void qkv_kernel(
    const float* __restrict__ feat,
    const float* __restrict__ Wqc, const float* __restrict__ bqc,
    const float* __restrict__ Wqe, const float* __restrict__ bqe,
    const float* __restrict__ bf1, const float* __restrict__ bf2,
    __hip_bfloat16* __restrict__ Qe, __hip_bfloat16* __restrict__ Ke,
    __hip_bfloat16* __restrict__ Vt)
{
    __shared__ float fl[4][64];
    __shared__ float cc[4][24];
    const int t = threadIdx.x;
    const int w = t >> 6, lane = t & 63;
    const int bn = blockIdx.x * 4 + w;
    const int b = bn >> 11, n = bn & (NN - 1);

    fl[w][lane] = feat[(size_t)bn * FD + lane];
    __syncthreads();

    if (t < 96) {                          // stage 1: compress [64]->[24] per node
        const int node = t / 24, j = t - node * 24;
        float a = bqc[j];
        #pragma unroll 8
        for (int d = 0; d < 64; ++d) a += fl[node][d] * Wqc[d * 24 + j];
        cc[node][j] = a;
    }
    __syncthreads();

    float v0 = bqe[lane], v1 = bqe[lane + 64], v2 = bqe[lane + 128];
    #pragma unroll
    for (int j = 0; j < 24; ++j) {         // stage 2: expand [24]->[192]
        const float c = cc[w][j];
        v0 += c * Wqe[j * 192 + lane];
        v1 += c * Wqe[j * 192 + 64 + lane];
        v2 += c * Wqe[j * 192 + 128 + lane];
    }

    const int h = lane >> 4, hi = lane & 15;
    const size_t rowQ = (((size_t)b * NH + h) * NN + n) * 32;
    Qe[rowQ + hi] = __float2bfloat16(v0 * (0.25f * L2E));  // fold 1/sqrt(hd), 1/ln2
    Ke[rowQ + hi] = __float2bfloat16(v1);
    Vt[(((size_t)b * NH + h) * HDD + hi) * NN + n] = __float2bfloat16(v2);

    // bias-factor extension + zero padding
    if (lane < 32) {
        const int hh = lane >> 3, c = lane & 7;
        const size_t r = (((size_t)b * NH + hh) * NN + n) * 32;
        Qe[r + 16 + c] = __float2bfloat16(bf1[((size_t)hh * NN + n) * 8 + c] * L2E);
        Qe[r + 24 + c] = __float2bfloat16(0.f);
    } else {
        const int hh = (lane - 32) >> 3, c = lane & 7;
        const size_t r = (((size_t)b * NH + hh) * NN + n) * 32;
        Ke[r + 16 + c] = __float2bfloat16(bf2[((size_t)hh * 8 + c) * NN + n]);
        Ke[r + 24 + c] = __float2bfloat16(0.f);
    }
}

// ---------------- Pass B: fused attention, split-K, max-free softmax, BARRIER-FREE loop.
// Block = (b, 32-query tile, key-split); 4 independent waves = 4 heads; each wave owns
// TWO 16-query fragments -> every K/V load feeds 2 MFMAs.
// Graph read per-lane as ONE fp16x8 (16B) per fragment-chunk: wave covers 16 rows x 64B
// = 16 fully-used sectors; the 4 head-waves read identical E addresses -> L1 hits.
// No LDS staging, no in-loop barriers: waves free-run, compiler pipelines with registers.
// S^T = mfma(K permuted-rows, Q): lane(ql,g) holds keys 8g..8g+7 of each 32-key chunk
// -> P already in x32 B-fragment layout -> single PV mfma, no shuffles.
__global__ __launch_bounds__(256, 4) void attn_kernel(
    const _Float16* __restrict__ E,
    const __hip_bfloat16* __restrict__ Qe, const __hip_bfloat16* __restrict__ Ke,
    const __hip_bfloat16* __restrict__ Vt,
    float* __restrict__ pacc, float* __restrict__ psum)
{
    __shared__ float ldsO[QB * 68];      // output transpose only

    const int bid = blockIdx.x;          // grid = BB * (NN/QB) * SPLIT = 1024
    const int split = bid & (SPLIT - 1);
    const int qt = (bid >> 2) & 63;
    const int b = bid >> 8;
    const int qb = qt << 5;
    const int kbase = split * KPB;
    const int t = threadIdx.x;
    const int hw = t >> 6;               // head
    const int lane = t & 63;
    const int ql = lane & 15;            // query-within-fragment / C col
    const int g  = lane >> 4;            // 16-lane group

    const size_t bhN = ((size_t)b * NH + hw) * NN;
    const bf16x8 qfA = *(const bf16x8*)(Qe + (bhN + qb + ql) * 32 + g * 8);
    const bf16x8 qfB = *(const bf16x8*)(Qe + (bhN + qb + 16 + ql) * 32 + g * 8);
    const __hip_bfloat16* kptr = Ke + bhN * 32;
    const __hip_bfloat16* vbase = Vt + (((size_t)b * NH + hw) * HDD + ql) * NN;
    const int krow = 8 * (ql >> 2) + (ql & 3);   // permuted key row within chunk

    // this lane's graph pointers: row (qb+ql) / (qb+16+ql), its 8 keys at +8g
    const _Float16* erA = E + ((size_t)b * NN + qb + ql) * NN + kbase + 8 * g;
    const _Float16* erB = erA + (size_t)16 * NN;

    float ssA = 0.f, ssB = 0.f;
    f32x4 accA = {0.f, 0.f, 0.f, 0.f}, accB = {0.f, 0.f, 0.f, 0.f};

    #pragma unroll 2
    for (int kt = 0; kt < KT; ++kt) {
        #pragma unroll
        for (int hf = 0; hf < 2; ++hf) {
            const int co = kt * 64 + hf * 32;          // chunk offset within split
            const int kb = kbase + co;
            const bf16x8 k0 = *(const bf16x8*)(kptr + (size_t)(kb + krow) * 32 + g * 8);
            const bf16x8 k1 = *(const bf16x8*)(kptr + (size_t)(kb + 4 + krow) * 32 + g * 8);
            const f16x8 eA = *(const f16x8*)(erA + co);
            const f16x8 eB = *(const f16x8*)(erB + co);
            const f32x4 z = {0.f, 0.f, 0.f, 0.f};
            f32x4 cA0 = __builtin_amdgcn_mfma_f32_16x16x32_bf16(k0, qfA, z, 0, 0, 0);
            f32x4 cA1 = __builtin_amdgcn_mfma_f32_16x16x32_bf16(k1, qfA, z, 0, 0, 0);
            f32x4 cB0 = __builtin_amdgcn_mfma_f32_16x16x32_bf16(k0, qfB, z, 0, 0, 0);
            f32x4 cB1 = __builtin_amdgcn_mfma_f32_16x16x32_bf16(k1, qfB, z, 0, 0, 0);
            #pragma unroll
            for (int j = 0; j < 4; ++j) {
                cA0[j] = __builtin_amdgcn_exp2f(cA0[j] + (float)eA[j]);
                cA1[j] = __builtin_amdgcn_exp2f(cA1[j] + (float)eA[4 + j]);
                cB0[j] = __builtin_amdgcn_exp2f(cB0[j] + (float)eB[j]);
                cB1[j] = __builtin_amdgcn_exp2f(cB1[j] + (float)eB[4 + j]);
                ssA += cA0[j] + cA1[j];
                ssB += cB0[j] + cB1[j];
            }
            union { unsigned u[4]; bf16x8 v; } pfA, pfB;
            pfA.u[0] = pk2(cA0[0], cA0[1]);  pfA.u[1] = pk2(cA0[2], cA0[3]);
            pfA.u[2] = pk2(cA1[0], cA1[1]);  pfA.u[3] = pk2(cA1[2], cA1[3]);
            pfB.u[0] = pk2(cB0[0], cB0[1]);  pfB.u[1] = pk2(cB0[2], cB0[3]);
            pfB.u[2] = pk2(cB1[0], cB1[1]);  pfB.u[3] = pk2(cB1[2], cB1[3]);
            const bf16x8 vf = *(const bf16x8*)(vbase + kb + 8 * g);   // shared by A and B
            accA = __builtin_amdgcn_mfma_f32_16x16x32_bf16(vf, pfA.v, accA, 0, 0, 0);
            accB = __builtin_amdgcn_mfma_f32_16x16x32_bf16(vf, pfB.v, accB, 0, 0, 0);
        }
    }

    // per-query sum of exps
    ssA += __shfl_xor(ssA, 16);  ssA += __shfl_xor(ssA, 32);
    ssB += __shfl_xor(ssB, 16);  ssB += __shfl_xor(ssB, 32);
    if (g == 0) {
        psum[((size_t)(split * BB + b) * NH + hw) * NN + qb + ql] = ssA;
        psum[((size_t)(split * BB + b) * NH + hw) * NN + qb + 16 + ql] = ssB;
    }

    // unnormalized partial context -> transpose via LDS -> coalesced f32x4 writes
    #pragma unroll
    for (int j = 0; j < 4; ++j) {
        ldsO[ql * 68 + hw * 16 + 4 * g + j] = accA[j];
        ldsO[(ql + 16) * 68 + hw * 16 + 4 * g + j] = accB[j];
    }
    __syncthreads();
    {
        const int r = t >> 3, c = (t & 7) * 8;
        const f32x4 o0 = *(const f32x4*)&ldsO[r * 68 + c];
        const f32x4 o1 = *(const f32x4*)&ldsO[r * 68 + c + 4];
        float* prow = pacc + ((size_t)(split * BB + b) * NN + qb + r) * FD + c;
        *(f32x4*)prow = o0;
        *(f32x4*)(prow + 4) = o1;
    }
}

// ---------------- Pass C: combine splits, out = LN((ctx @ Woc + boc) @ Woe + boe + res)
__global__ __launch_bounds__(256) void out_kernel(
    const float* __restrict__ pacc, const float* __restrict__ psum,
    const float* __restrict__ feat,
    const float* __restrict__ Woc, const float* __restrict__ boc,
    const float* __restrict__ Woe, const float* __restrict__ boe,
    const float* __restrict__ lng, const float* __restrict__ lnb,
    float* __restrict__ out)
{
    __shared__ float cl[4][64];
    __shared__ float co[4][8];
    const int t = threadIdx.x;
    const int w = t >> 6, d = t & 63;
    const int node = blockIdx.x * 4 + w;
    const int b = node >> 11, n = node & (NN - 1);
    const int h = d >> 4;

    float a = 0.f, sh = 0.f;
    #pragma unroll
    for (int sp = 0; sp < SPLIT; ++sp) {
        a  += pacc[((size_t)sp * BB * NN + node) * FD + d];
        sh += psum[((size_t)(sp * BB + b) * NH + h) * NN + n];
    }
    cl[w][d] = a / sh;
    __syncthreads();

    if (t < 32) {                          // stage 1: compress [64]->[8] per node
        const int nd = t >> 3, j = t & 7;
        float s = boc[j];
        #pragma unroll 8
        for (int dd = 0; dd < 64; ++dd) s += cl[nd][dd] * Woc[dd * 8 + j];
        co[nd][j] = s;
    }
    __syncthreads();

    float o = boe[d];                      // stage 2: expand [8]->[64]
    #pragma unroll
    for (int j = 0; j < 8; ++j) o += co[w][j] * Woe[j * 64 + d];
    o += feat[(size_t)node * FD + d];

    const float mu = wsum(o) * (1.f / 64.f);
    const float df = o - mu;
    const float va = wsum(df * df) * (1.f / 64.f);
    out[(size_t)node * FD + d] = df * rsqrtf(va + 1e-5f) * lng[d] + lnb[d];
    if (blockIdx.x == 0 && t == 0)
        out[(size_t)BB * NN * FD] = 4.8828125e-9f;  // 1e-5 * mean(attn) = 1e-5 / N exactly
}

extern "C" void kernel_launch(void* const* d_in, const int* in_sizes, int n_in,
                              void* d_out, int out_size, void* d_ws, size_t ws_size,
                              hipStream_t stream) {
    const float* feat   = (const float*)d_in[0];
    const float* fixedg = (const float*)d_in[1];
    const float* learng = (const float*)d_in[2];
    const float* Wqc = (const float*)d_in[3];
    const float* bqc = (const float*)d_in[4];
    const float* Wqe = (const float*)d_in[5];
    const float* bqe = (const float*)d_in[6];
    const float* Woc = (const float*)d_in[7];
    const float* boc = (const float*)d_in[8];
    const float* Woe = (const float*)d_in[9];
    const float* boe = (const float*)d_in[10];
    const float* bf1 = (const float*)d_in[11];
    const float* bf2 = (const float*)d_in[12];
    const float* gfus = (const float*)d_in[13];
    const float* lng = (const float*)d_in[14];
    const float* lnb = (const float*)d_in[15];

    char* ws = (char*)d_ws;
    __hip_bfloat16* Qe = (__hip_bfloat16*)ws;                       // 2 MB
    __hip_bfloat16* Ke = Qe + (size_t)BB * NH * NN * 32;            // 2 MB
    __hip_bfloat16* Vt = Ke + (size_t)BB * NH * NN * 32;            // 1 MB
    _Float16* E = (_Float16*)(Vt + (size_t)BB * NH * HDD * NN);     // B*N*N fp16 = 33.5 MB
    float* pacc = (float*)(E + (size_t)BB * NN * NN);               // 8.4 MB
    float* psum = pacc + (size_t)SPLIT * BB * NN * FD;              // 0.5 MB
    float* out = (float*)d_out;

    hipLaunchKernelGGL(blend_kernel, dim3(BB * NN * NN / (256 * 32)), dim3(256), 0, stream,
                       learng, fixedg, gfus, E);
    hipLaunchKernelGGL(qkv_kernel, dim3(BB * NN / 4), dim3(256), 0, stream,
                       feat, Wqc, bqc, Wqe, bqe, bf1, bf2, Qe, Ke, Vt);
    hipLaunchKernelGGL(attn_kernel, dim3(BB * (NN / QB) * SPLIT), dim3(256), 0, stream,
                       E, Qe, Ke, Vt, pacc, psum);
    hipLaunchKernelGGL(out_kernel, dim3(BB * NN / 4), dim3(256), 0, stream,
                       pacc, psum, feat, Woc, boc, Woe, boe, lng, lnb, out);
}